// Round 1
// baseline (1136.979 us; speedup 1.0000x reference)
//
#include <hip/hip_runtime.h>
#include <hip/hip_bf16.h>

#define N_NODES 50000
#define N_EDGES 800000

// ---------------- degree count ----------------
__global__ void count_deg_k(const int* __restrict__ src, const int* __restrict__ dst,
                            int n_edges, int* __restrict__ deg_out, int* __restrict__ deg_in) {
    int i = blockIdx.x * blockDim.x + threadIdx.x;
    if (i < n_edges) {
        atomicAdd(&deg_out[src[i]], 1);
        atomicAdd(&deg_in[dst[i]], 1);
    }
}

// ---------------- norms ----------------
__global__ void norm_k(const int* __restrict__ deg_out, const int* __restrict__ deg_in,
                       float* __restrict__ ns, float* __restrict__ nd, int n) {
    int i = blockIdx.x * blockDim.x + threadIdx.x;
    if (i < n) {
        ns[i] = 1.0f / sqrtf((float)max(deg_out[i], 1));
        nd[i] = 1.0f / sqrtf((float)max(deg_in[i], 1));
    }
}

// ---------------- exclusive scan (single block, 1024 threads) ----------------
__global__ void scan_k(const int* __restrict__ deg, int* __restrict__ row_start,
                       int* __restrict__ cursor, int n) {
    __shared__ int sm[1024];
    __shared__ int carry_s;
    int tid = threadIdx.x;
    if (tid == 0) carry_s = 0;
    __syncthreads();
    for (int base = 0; base < n; base += 1024) {
        int i = base + tid;
        int v = (i < n) ? deg[i] : 0;
        sm[tid] = v;
        __syncthreads();
        for (int off = 1; off < 1024; off <<= 1) {
            int t = (tid >= off) ? sm[tid - off] : 0;
            __syncthreads();
            sm[tid] += t;
            __syncthreads();
        }
        int excl = sm[tid] - v;
        int carry = carry_s;
        int chunk_total = sm[1023];
        if (i < n) {
            int o = carry + excl;
            row_start[i] = o;
            cursor[i] = o;
        }
        __syncthreads();
        if (tid == 0) carry_s = carry + chunk_total;
        __syncthreads();
    }
    if (tid == 0) row_start[n] = carry_s;
}

// ---------------- CSR fill ----------------
__global__ void fill_csr_k(const int* __restrict__ src, const int* __restrict__ dst,
                           int n_edges, int* __restrict__ cursor, int* __restrict__ edge_src) {
    int i = blockIdx.x * blockDim.x + threadIdx.x;
    if (i < n_edges) {
        int pos = atomicAdd(&cursor[dst[i]], 1);
        edge_src[pos] = src[i];
    }
}

// ---------------- GEMM with fused A-row preprocessing ----------------
// C[M,N] = pre(A)[M,K] @ W[K,N]
// mode 0: a = A[v][k] * ns[v]
// mode 1: a = relu(A[v][k]*nd[v] + bias[k]) * ns[v]
template <int BN>
__global__ __launch_bounds__(256) void gemm_pre_k(
    const float* __restrict__ A, const float* __restrict__ W, float* __restrict__ C,
    int M, int K, int N,
    const float* __restrict__ ns, const float* __restrict__ nd,
    const float* __restrict__ bias, int mode) {
    constexpr int BM = 128, BK = 16;
    constexpr int CG = BN / 64;  // column groups of 64 (1 or 2)
    __shared__ __attribute__((aligned(16))) float As[BK][BM + 4];
    __shared__ __attribute__((aligned(16))) float Bs[BK][BN + 4];
    const int t = threadIdx.x;
    const int tx = t & 15, ty = t >> 4;
    const int m0 = blockIdx.x * BM;
    const int n0 = blockIdx.y * BN;

    float acc[2][CG][4][4];
#pragma unroll
    for (int rg = 0; rg < 2; ++rg)
#pragma unroll
        for (int g = 0; g < CG; ++g)
#pragma unroll
            for (int i = 0; i < 4; ++i)
#pragma unroll
                for (int j = 0; j < 4; ++j) acc[rg][g][i][j] = 0.f;

    for (int k0 = 0; k0 < K; k0 += BK) {
        // ---- A tile: BM x BK = 2048 floats, 2 float4/thread, preprocess, store transposed
#pragma unroll
        for (int l = 0; l < 2; ++l) {
            int f = t + l * 256;          // 0..511
            int row = f >> 2;             // 0..127
            int c4 = (f & 3) << 2;        // 0,4,8,12
            int grow = m0 + row;
            float4 v = make_float4(0.f, 0.f, 0.f, 0.f);
            if (grow < M) {
                v = *(const float4*)&A[(size_t)grow * K + k0 + c4];
                float s = ns[grow];
                if (mode == 1) {
                    float d = nd[grow];
                    float4 bv = *(const float4*)&bias[k0 + c4];
                    v.x = fmaxf(fmaf(v.x, d, bv.x), 0.f);
                    v.y = fmaxf(fmaf(v.y, d, bv.y), 0.f);
                    v.z = fmaxf(fmaf(v.z, d, bv.z), 0.f);
                    v.w = fmaxf(fmaf(v.w, d, bv.w), 0.f);
                }
                v.x *= s; v.y *= s; v.z *= s; v.w *= s;
            }
            As[c4 + 0][row] = v.x;
            As[c4 + 1][row] = v.y;
            As[c4 + 2][row] = v.z;
            As[c4 + 3][row] = v.w;
        }
        // ---- B tile: BK x BN
#pragma unroll
        for (int l = 0; l < (BK * BN) / 1024; ++l) {
            int f = t + l * 256;
            int r = f / (BN / 4);
            int c4 = (f % (BN / 4)) << 2;
            *(float4*)&Bs[r][c4] = *(const float4*)&W[(size_t)(k0 + r) * N + n0 + c4];
        }
        __syncthreads();
#pragma unroll
        for (int kk = 0; kk < BK; ++kk) {
            float ar[2][4];
#pragma unroll
            for (int rg = 0; rg < 2; ++rg) {
                float4 a = *(const float4*)&As[kk][ty * 4 + rg * 64];
                ar[rg][0] = a.x; ar[rg][1] = a.y; ar[rg][2] = a.z; ar[rg][3] = a.w;
            }
            float br[CG][4];
#pragma unroll
            for (int g = 0; g < CG; ++g) {
                float4 b = *(const float4*)&Bs[kk][tx * 4 + g * 64];
                br[g][0] = b.x; br[g][1] = b.y; br[g][2] = b.z; br[g][3] = b.w;
            }
#pragma unroll
            for (int rg = 0; rg < 2; ++rg)
#pragma unroll
                for (int g = 0; g < CG; ++g)
#pragma unroll
                    for (int i = 0; i < 4; ++i)
#pragma unroll
                        for (int j = 0; j < 4; ++j)
                            acc[rg][g][i][j] = fmaf(ar[rg][i], br[g][j], acc[rg][g][i][j]);
        }
        __syncthreads();
    }
    // ---- epilogue
#pragma unroll
    for (int rg = 0; rg < 2; ++rg)
#pragma unroll
        for (int i = 0; i < 4; ++i) {
            int row = m0 + ty * 4 + rg * 64 + i;
            if (row < M) {
#pragma unroll
                for (int g = 0; g < CG; ++g) {
                    float4 v = make_float4(acc[rg][g][i][0], acc[rg][g][i][1],
                                           acc[rg][g][i][2], acc[rg][g][i][3]);
                    *(float4*)&C[(size_t)row * N + n0 + tx * 4 + g * 64] = v;
                }
            }
        }
}

// ---------------- CSR aggregation: one wave per node ----------------
template <int VEC>  // floats per lane: dim = 64*VEC
__global__ void aggregate_k(const float* __restrict__ tmp, float* __restrict__ agg,
                            const int* __restrict__ row_start, const int* __restrict__ edge_src,
                            int n_nodes, int dim) {
    int w = (blockIdx.x * blockDim.x + threadIdx.x) >> 6;
    int lane = threadIdx.x & 63;
    if (w >= n_nodes) return;
    int s = row_start[w], e = row_start[w + 1];
    int col = lane * VEC;
    float acc[VEC];
#pragma unroll
    for (int j = 0; j < VEC; ++j) acc[j] = 0.f;
    for (int i = s; i < e; ++i) {
        int u = edge_src[i];
        const float* p = tmp + (size_t)u * dim + col;
        if (VEC == 4) {
            float4 v = *(const float4*)p;
            acc[0] += v.x; acc[1] += v.y; acc[2] += v.z; acc[3] += v.w;
        } else if (VEC == 2) {
            float2 v = *(const float2*)p;
            acc[0] += v.x; acc[1] += v.y;
        } else {
            acc[0] += *p;
        }
    }
    float* q = agg + (size_t)w * dim + col;
    if (VEC == 4) {
        *(float4*)q = make_float4(acc[0], acc[1], acc[2], acc[3]);
    } else if (VEC == 2) {
        *(float2*)q = make_float2(acc[0], acc[1]);
    } else {
        *q = acc[0];
    }
}

// ---------------- finalize: out = agg*nd[row] + bias[col] (float4) ----------------
__global__ void finalize_k(const float* __restrict__ agg, const float* __restrict__ nd,
                           const float* __restrict__ bias, float* __restrict__ out,
                           int n4, int shift) {  // n4 = rows*dim/4, shift=log2(dim/4)
    int idx = blockIdx.x * blockDim.x + threadIdx.x;
    if (idx >= n4) return;
    int row = idx >> shift;
    int c4 = (idx & ((1 << shift) - 1)) << 2;
    float d = nd[row];
    float4 v = *(const float4*)&agg[(size_t)idx * 4];
    float4 b = *(const float4*)&bias[c4];
    float4 o;
    o.x = fmaf(v.x, d, b.x);
    o.y = fmaf(v.y, d, b.y);
    o.z = fmaf(v.z, d, b.z);
    o.w = fmaf(v.w, d, b.w);
    *(float4*)&out[(size_t)idx * 4] = o;
}

extern "C" void kernel_launch(void* const* d_in, const int* in_sizes, int n_in,
                              void* d_out, int out_size, void* d_ws, size_t ws_size,
                              hipStream_t stream) {
    const float* features = (const float*)d_in[0];
    const int* src = (const int*)d_in[1];
    const int* dst = (const int*)d_in[2];
    const float* W0 = (const float*)d_in[3];
    const float* b0 = (const float*)d_in[4];
    const float* W1 = (const float*)d_in[5];
    const float* b1 = (const float*)d_in[6];
    const float* W2 = (const float*)d_in[7];
    const float* b2 = (const float*)d_in[8];
    const float* W3 = (const float*)d_in[9];
    const float* b3 = (const float*)d_in[10];
    float* out = (float*)d_out;

    // workspace carve (total ~102 MiB)
    char* p = (char*)d_ws;
    auto alloc = [&](size_t bytes) {
        void* r = (void*)p;
        p += (bytes + 255) & ~(size_t)255;
        return r;
    };
    float* bufA = (float*)alloc((size_t)N_NODES * 256 * 4);
    float* bufB = (float*)alloc((size_t)N_NODES * 256 * 4);
    int* edge_src = (int*)alloc((size_t)N_EDGES * 4);
    int* row_start = (int*)alloc((size_t)(N_NODES + 1) * 4);
    int* cursor = (int*)alloc((size_t)N_NODES * 4);
    int* degO = (int*)alloc((size_t)N_NODES * 4);
    int* degI = (int*)alloc((size_t)N_NODES * 4);
    float* ns = (float*)alloc((size_t)N_NODES * 4);
    float* nd = (float*)alloc((size_t)N_NODES * 4);

    // ---- graph preprocessing (per call; ws is re-poisoned) ----
    hipMemsetAsync(degO, 0, (size_t)N_NODES * 4, stream);
    hipMemsetAsync(degI, 0, (size_t)N_NODES * 4, stream);
    count_deg_k<<<(N_EDGES + 255) / 256, 256, 0, stream>>>(src, dst, N_EDGES, degO, degI);
    norm_k<<<(N_NODES + 255) / 256, 256, 0, stream>>>(degO, degI, ns, nd, N_NODES);
    scan_k<<<1, 1024, 0, stream>>>(degI, row_start, cursor, N_NODES);
    fill_csr_k<<<(N_EDGES + 255) / 256, 256, 0, stream>>>(src, dst, N_EDGES, cursor, edge_src);

    const int gm = (N_NODES + 127) / 128;  // 391
    const int aggBlocks = (N_NODES + 3) / 4;  // 4 waves/block

    // ---- layer 0: 512 -> 256 (relu folded into next GEMM) ----
    gemm_pre_k<128><<<dim3(gm, 2), 256, 0, stream>>>(features, W0, bufA, N_NODES, 512, 256,
                                                     ns, nullptr, nullptr, 0);
    aggregate_k<4><<<aggBlocks, 256, 0, stream>>>(bufA, bufB, row_start, edge_src, N_NODES, 256);

    // ---- layer 1: 256 -> 256 ----
    gemm_pre_k<128><<<dim3(gm, 2), 256, 0, stream>>>(bufB, W1, bufA, N_NODES, 256, 256,
                                                     ns, nd, b0, 1);
    aggregate_k<4><<<aggBlocks, 256, 0, stream>>>(bufA, bufB, row_start, edge_src, N_NODES, 256);

    // ---- layer 2: 256 -> 128 (aspect_embed, no relu) ----
    gemm_pre_k<128><<<dim3(gm, 1), 256, 0, stream>>>(bufB, W2, bufA, N_NODES, 256, 128,
                                                     ns, nd, b1, 1);
    aggregate_k<2><<<aggBlocks, 256, 0, stream>>>(bufA, bufB, row_start, edge_src, N_NODES, 128);
    // aspect_embed = agg2*nd + b2 -> d_out[0 : 50000*128]
    finalize_k<<<(N_NODES * 128 / 4 + 255) / 256, 256, 0, stream>>>(bufB, nd, b2, out,
                                                                   N_NODES * 128 / 4, 5);

    // ---- layer 3: 128 -> 64 (input = aspect_embed from d_out) ----
    gemm_pre_k<64><<<dim3(gm, 1), 256, 0, stream>>>(out, W3, bufA, N_NODES, 128, 64,
                                                    ns, nullptr, nullptr, 0);
    aggregate_k<1><<<aggBlocks, 256, 0, stream>>>(bufA, bufB, row_start, edge_src, N_NODES, 64);
    // h = agg3*nd + b3 -> d_out[50000*128 : ]
    finalize_k<<<(N_NODES * 64 / 4 + 255) / 256, 256, 0, stream>>>(bufB, nd, b3,
                                                                  out + (size_t)N_NODES * 128,
                                                                  N_NODES * 64 / 4, 4);
}

// Round 2
// 1007.067 us; speedup vs baseline: 1.1290x; 1.1290x over previous
//
#include <hip/hip_runtime.h>
#include <hip/hip_bf16.h>

#define N_NODES 50000
#define N_EDGES 800000

// ---------------- degree count ----------------
__global__ void count_deg_k(const int* __restrict__ src, const int* __restrict__ dst,
                            int n_edges, int* __restrict__ deg_out, int* __restrict__ deg_in) {
    int i = blockIdx.x * blockDim.x + threadIdx.x;
    if (i < n_edges) {
        atomicAdd(&deg_out[src[i]], 1);
        atomicAdd(&deg_in[dst[i]], 1);
    }
}

// ---------------- norms ----------------
__global__ void norm_k(const int* __restrict__ deg_out, const int* __restrict__ deg_in,
                       float* __restrict__ ns, float* __restrict__ nd, int n) {
    int i = blockIdx.x * blockDim.x + threadIdx.x;
    if (i < n) {
        ns[i] = 1.0f / sqrtf((float)max(deg_out[i], 1));
        nd[i] = 1.0f / sqrtf((float)max(deg_in[i], 1));
    }
}

// ---------------- exclusive scan (single block, 1024 threads) ----------------
__global__ void scan_k(const int* __restrict__ deg, int* __restrict__ row_start,
                       int* __restrict__ cursor, int n) {
    __shared__ int sm[1024];
    __shared__ int carry_s;
    int tid = threadIdx.x;
    if (tid == 0) carry_s = 0;
    __syncthreads();
    for (int base = 0; base < n; base += 1024) {
        int i = base + tid;
        int v = (i < n) ? deg[i] : 0;
        sm[tid] = v;
        __syncthreads();
        for (int off = 1; off < 1024; off <<= 1) {
            int t = (tid >= off) ? sm[tid - off] : 0;
            __syncthreads();
            sm[tid] += t;
            __syncthreads();
        }
        int excl = sm[tid] - v;
        int carry = carry_s;
        int chunk_total = sm[1023];
        if (i < n) {
            int o = carry + excl;
            row_start[i] = o;
            cursor[i] = o;
        }
        __syncthreads();
        if (tid == 0) carry_s = carry + chunk_total;
        __syncthreads();
    }
    if (tid == 0) row_start[n] = carry_s;
}

// ---------------- CSR fill ----------------
__global__ void fill_csr_k(const int* __restrict__ src, const int* __restrict__ dst,
                           int n_edges, int* __restrict__ cursor, int* __restrict__ edge_src) {
    int i = blockIdx.x * blockDim.x + threadIdx.x;
    if (i < n_edges) {
        int pos = atomicAdd(&cursor[dst[i]], 1);
        edge_src[pos] = src[i];
    }
}

// ---------------- GEMM: C[M,N] = ns[row] * (A[M,K] @ W[K,N]) ----------------
// BM=64, 256 threads, per-thread 4 rows x (4*CG) cols. ns applied in epilogue.
template <int BN>
__global__ __launch_bounds__(256) void gemm_ns_k(
    const float* __restrict__ A, const float* __restrict__ W, float* __restrict__ C,
    int M, int K, int N, const float* __restrict__ ns) {
    constexpr int BM = 64, BK = 16;
    constexpr int CG = BN / 64;  // column groups of 64 (1 or 2)
    __shared__ __attribute__((aligned(16))) float As[BK][BM + 4];
    __shared__ __attribute__((aligned(16))) float Bs[BK][BN + 4];
    const int t = threadIdx.x;
    const int tx = t & 15, ty = t >> 4;  // tx: col group 0..15, ty: row group 0..15
    const int m0 = blockIdx.x * BM;
    const int n0 = blockIdx.y * BN;

    float acc[CG][4][4];
#pragma unroll
    for (int g = 0; g < CG; ++g)
#pragma unroll
        for (int i = 0; i < 4; ++i)
#pragma unroll
            for (int j = 0; j < 4; ++j) acc[g][i][j] = 0.f;

    // A staging coords: 1 float4/thread (BM*BK = 1024 floats)
    const int a_row = t >> 2;         // 0..63
    const int a_c4 = (t & 3) << 2;    // 0,4,8,12

    for (int k0 = 0; k0 < K; k0 += BK) {
        // ---- A tile: raw copy, stored transposed As[k][row]
        {
            int grow = m0 + a_row;
            float4 v = make_float4(0.f, 0.f, 0.f, 0.f);
            if (grow < M) v = *(const float4*)&A[(size_t)grow * K + k0 + a_c4];
            As[a_c4 + 0][a_row] = v.x;
            As[a_c4 + 1][a_row] = v.y;
            As[a_c4 + 2][a_row] = v.z;
            As[a_c4 + 3][a_row] = v.w;
        }
        // ---- B tile: BK x BN row-major
#pragma unroll
        for (int l = 0; l < (BK * BN) / 1024; ++l) {
            int f = t + l * 256;
            int r = f / (BN / 4);
            int c4 = (f % (BN / 4)) << 2;
            *(float4*)&Bs[r][c4] = *(const float4*)&W[(size_t)(k0 + r) * N + n0 + c4];
        }
        __syncthreads();
#pragma unroll
        for (int kk = 0; kk < BK; ++kk) {
            float4 a = *(const float4*)&As[kk][ty * 4];
            float ar[4] = {a.x, a.y, a.z, a.w};
            float br[CG][4];
#pragma unroll
            for (int g = 0; g < CG; ++g) {
                float4 b = *(const float4*)&Bs[kk][tx * 4 + g * 64];
                br[g][0] = b.x; br[g][1] = b.y; br[g][2] = b.z; br[g][3] = b.w;
            }
#pragma unroll
            for (int g = 0; g < CG; ++g)
#pragma unroll
                for (int i = 0; i < 4; ++i)
#pragma unroll
                    for (int j = 0; j < 4; ++j)
                        acc[g][i][j] = fmaf(ar[i], br[g][j], acc[g][i][j]);
        }
        __syncthreads();
    }
    // ---- epilogue: scale by ns[row]
#pragma unroll
    for (int i = 0; i < 4; ++i) {
        int row = m0 + ty * 4 + i;
        if (row < M) {
            float s = ns[row];
#pragma unroll
            for (int g = 0; g < CG; ++g) {
                float4 v = make_float4(acc[g][i][0] * s, acc[g][i][1] * s,
                                       acc[g][i][2] * s, acc[g][i][3] * s);
                *(float4*)&C[(size_t)row * N + n0 + tx * 4 + g * 64] = v;
            }
        }
    }
}

// ---------------- CSR aggregation + fused epilogue ----------------
// out[w] = act(sum_{e in dst==w} tmp[src[e]] * nd[w] + bias), one wave per node
template <int VEC, int RELU>  // floats per lane: dim = 64*VEC
__global__ void agg_ep_k(const float* __restrict__ tmp, float* __restrict__ out,
                         const int* __restrict__ row_start, const int* __restrict__ edge_src,
                         const float* __restrict__ nd, const float* __restrict__ bias,
                         int n_nodes, int dim) {
    int w = (blockIdx.x * blockDim.x + threadIdx.x) >> 6;
    int lane = threadIdx.x & 63;
    if (w >= n_nodes) return;
    int s = row_start[w], e = row_start[w + 1];
    int col = lane * VEC;
    float acc0[VEC], acc1[VEC];
#pragma unroll
    for (int j = 0; j < VEC; ++j) { acc0[j] = 0.f; acc1[j] = 0.f; }
    int i = s;
    for (; i + 1 < e; i += 2) {
        int u0 = edge_src[i];
        int u1 = edge_src[i + 1];
        const float* p0 = tmp + (size_t)u0 * dim + col;
        const float* p1 = tmp + (size_t)u1 * dim + col;
        if (VEC == 4) {
            float4 v0 = *(const float4*)p0;
            float4 v1 = *(const float4*)p1;
            acc0[0] += v0.x; acc0[1] += v0.y; acc0[2] += v0.z; acc0[3] += v0.w;
            acc1[0] += v1.x; acc1[1] += v1.y; acc1[2] += v1.z; acc1[3] += v1.w;
        } else if (VEC == 2) {
            float2 v0 = *(const float2*)p0;
            float2 v1 = *(const float2*)p1;
            acc0[0] += v0.x; acc0[1] += v0.y;
            acc1[0] += v1.x; acc1[1] += v1.y;
        } else {
            acc0[0] += *p0;
            acc1[0] += *p1;
        }
    }
    if (i < e) {
        int u = edge_src[i];
        const float* p = tmp + (size_t)u * dim + col;
        if (VEC == 4) {
            float4 v = *(const float4*)p;
            acc0[0] += v.x; acc0[1] += v.y; acc0[2] += v.z; acc0[3] += v.w;
        } else if (VEC == 2) {
            float2 v = *(const float2*)p;
            acc0[0] += v.x; acc0[1] += v.y;
        } else {
            acc0[0] += *p;
        }
    }
    float d = nd[w];
    float r[VEC];
#pragma unroll
    for (int j = 0; j < VEC; ++j) {
        float v = fmaf(acc0[j] + acc1[j], d, bias[col + j]);
        r[j] = RELU ? fmaxf(v, 0.f) : v;
    }
    float* q = out + (size_t)w * dim + col;
    if (VEC == 4) {
        *(float4*)q = make_float4(r[0], r[1], r[2], r[3]);
    } else if (VEC == 2) {
        *(float2*)q = make_float2(r[0], r[1]);
    } else {
        *q = r[0];
    }
}

extern "C" void kernel_launch(void* const* d_in, const int* in_sizes, int n_in,
                              void* d_out, int out_size, void* d_ws, size_t ws_size,
                              hipStream_t stream) {
    const float* features = (const float*)d_in[0];
    const int* src = (const int*)d_in[1];
    const int* dst = (const int*)d_in[2];
    const float* W0 = (const float*)d_in[3];
    const float* b0 = (const float*)d_in[4];
    const float* W1 = (const float*)d_in[5];
    const float* b1 = (const float*)d_in[6];
    const float* W2 = (const float*)d_in[7];
    const float* b2 = (const float*)d_in[8];
    const float* W3 = (const float*)d_in[9];
    const float* b3 = (const float*)d_in[10];
    float* out = (float*)d_out;

    // workspace carve
    char* p = (char*)d_ws;
    auto alloc = [&](size_t bytes) {
        void* r = (void*)p;
        p += (bytes + 255) & ~(size_t)255;
        return r;
    };
    float* tmpA = (float*)alloc((size_t)N_NODES * 256 * 4);  // GEMM outputs (pre-agg)
    float* hB = (float*)alloc((size_t)N_NODES * 256 * 4);    // layer activations
    int* edge_src = (int*)alloc((size_t)N_EDGES * 4);
    int* row_start = (int*)alloc((size_t)(N_NODES + 1) * 4);
    int* cursor = (int*)alloc((size_t)N_NODES * 4);
    int* degO = (int*)alloc((size_t)N_NODES * 4);
    int* degI = (int*)alloc((size_t)N_NODES * 4);
    float* ns = (float*)alloc((size_t)N_NODES * 4);
    float* nd = (float*)alloc((size_t)N_NODES * 4);

    // ---- graph preprocessing ----
    hipMemsetAsync(degO, 0, (size_t)N_NODES * 4, stream);
    hipMemsetAsync(degI, 0, (size_t)N_NODES * 4, stream);
    count_deg_k<<<(N_EDGES + 255) / 256, 256, 0, stream>>>(src, dst, N_EDGES, degO, degI);
    norm_k<<<(N_NODES + 255) / 256, 256, 0, stream>>>(degO, degI, ns, nd, N_NODES);
    scan_k<<<1, 1024, 0, stream>>>(degI, row_start, cursor, N_NODES);
    fill_csr_k<<<(N_EDGES + 255) / 256, 256, 0, stream>>>(src, dst, N_EDGES, cursor, edge_src);

    const int gm = (N_NODES + 63) / 64;       // 782
    const int aggBlocks = (N_NODES + 3) / 4;  // 4 waves/block

    // ---- layer 0: 512 -> 256 ----
    gemm_ns_k<128><<<dim3(gm, 2), 256, 0, stream>>>(features, W0, tmpA, N_NODES, 512, 256, ns);
    agg_ep_k<4, 1><<<aggBlocks, 256, 0, stream>>>(tmpA, hB, row_start, edge_src, nd, b0,
                                                  N_NODES, 256);

    // ---- layer 1: 256 -> 256 ----
    gemm_ns_k<128><<<dim3(gm, 2), 256, 0, stream>>>(hB, W1, tmpA, N_NODES, 256, 256, ns);
    agg_ep_k<4, 1><<<aggBlocks, 256, 0, stream>>>(tmpA, hB, row_start, edge_src, nd, b1,
                                                  N_NODES, 256);

    // ---- layer 2: 256 -> 128 (aspect_embed -> d_out[0:]) ----
    gemm_ns_k<128><<<dim3(gm, 1), 256, 0, stream>>>(hB, W2, tmpA, N_NODES, 256, 128, ns);
    agg_ep_k<2, 0><<<aggBlocks, 256, 0, stream>>>(tmpA, out, row_start, edge_src, nd, b2,
                                                  N_NODES, 128);

    // ---- layer 3: 128 -> 64 (h -> d_out[50000*128:]) ----
    gemm_ns_k<64><<<dim3(gm, 1), 256, 0, stream>>>(out, W3, tmpA, N_NODES, 128, 64, ns);
    agg_ep_k<1, 0><<<aggBlocks, 256, 0, stream>>>(tmpA, out + (size_t)N_NODES * 128, row_start,
                                                  edge_src, nd, b3, N_NODES, 64);
}

// Round 3
// 865.100 us; speedup vs baseline: 1.3143x; 1.1641x over previous
//
#include <hip/hip_runtime.h>
#include <hip/hip_bf16.h>

#define N_NODES 50000
#define N_EDGES 800000

typedef unsigned short ushort_t;
typedef unsigned int uint_t;
typedef __attribute__((ext_vector_type(8))) short short8;
typedef __attribute__((ext_vector_type(4))) float f32x4;

// ---------------- bf16 split helpers ----------------
__device__ inline ushort_t bf16_rne(float x) {
    uint_t u = __float_as_uint(x);
    uint_t r = (u + 0x7fffu + ((u >> 16) & 1u)) >> 16;
    return (ushort_t)r;
}
__device__ inline void split1(float x, ushort_t& h, ushort_t& l) {
    ushort_t hh = bf16_rne(x);
    float fh = __uint_as_float((uint_t)hh << 16);
    h = hh;
    l = bf16_rne(x - fh);
}

// ---------------- degree count ----------------
__global__ void count_deg_k(const int* __restrict__ src, const int* __restrict__ dst,
                            int n_edges, int* __restrict__ deg_out, int* __restrict__ deg_in) {
    int i = blockIdx.x * blockDim.x + threadIdx.x;
    if (i < n_edges) {
        atomicAdd(&deg_out[src[i]], 1);
        atomicAdd(&deg_in[dst[i]], 1);
    }
}

// ---------------- norms ----------------
__global__ void norm_k(const int* __restrict__ deg_out, const int* __restrict__ deg_in,
                       float* __restrict__ ns, float* __restrict__ nd, int n) {
    int i = blockIdx.x * blockDim.x + threadIdx.x;
    if (i < n) {
        ns[i] = 1.0f / sqrtf((float)max(deg_out[i], 1));
        nd[i] = 1.0f / sqrtf((float)max(deg_in[i], 1));
    }
}

// ---------------- exclusive scan (single block, 1024 threads) ----------------
__global__ void scan_k(const int* __restrict__ deg, int* __restrict__ row_start,
                       int* __restrict__ cursor, int n) {
    __shared__ int sm[1024];
    __shared__ int carry_s;
    int tid = threadIdx.x;
    if (tid == 0) carry_s = 0;
    __syncthreads();
    for (int base = 0; base < n; base += 1024) {
        int i = base + tid;
        int v = (i < n) ? deg[i] : 0;
        sm[tid] = v;
        __syncthreads();
        for (int off = 1; off < 1024; off <<= 1) {
            int t = (tid >= off) ? sm[tid - off] : 0;
            __syncthreads();
            sm[tid] += t;
            __syncthreads();
        }
        int excl = sm[tid] - v;
        int carry = carry_s;
        int chunk_total = sm[1023];
        if (i < n) {
            int o = carry + excl;
            row_start[i] = o;
            cursor[i] = o;
        }
        __syncthreads();
        if (tid == 0) carry_s = carry + chunk_total;
        __syncthreads();
    }
    if (tid == 0) row_start[n] = carry_s;
}

// ---------------- CSR fill ----------------
__global__ void fill_csr_k(const int* __restrict__ src, const int* __restrict__ dst,
                           int n_edges, int* __restrict__ cursor, int* __restrict__ edge_src) {
    int i = blockIdx.x * blockDim.x + threadIdx.x;
    if (i < n_edges) {
        int pos = atomicAdd(&cursor[dst[i]], 1);
        edge_src[pos] = src[i];
    }
}

// ---------------- split fp32 matrix -> hi/lo bf16 planes (same layout) ----------------
__global__ void split4_k(const float* __restrict__ X, ushort_t* __restrict__ hi,
                         ushort_t* __restrict__ lo, int n4) {
    int i = blockIdx.x * blockDim.x + threadIdx.x;
    if (i >= n4) return;
    float4 v = ((const float4*)X)[i];
    ushort4 h, l;
    split1(v.x, h.x, l.x);
    split1(v.y, h.y, l.y);
    split1(v.z, h.z, l.z);
    split1(v.w, h.w, l.w);
    ((ushort4*)hi)[i] = h;
    ((ushort4*)lo)[i] = l;
}

// ---------------- split + transpose weights: W[K][N] -> Wt planes [N][K] ----------------
__global__ void split_wt_k(const float* __restrict__ W, ushort_t* __restrict__ hi,
                           ushort_t* __restrict__ lo, int K, int N) {
    int idx = blockIdx.x * blockDim.x + threadIdx.x;
    if (idx >= K * N) return;
    int n = idx / K;
    int k = idx - n * K;
    float x = W[(size_t)k * N + n];
    split1(x, hi[idx], lo[idx]);
}

// ---------------- MFMA GEMM: C[M,N] = ns[row] * (A @ W), bf16x2 3-pass ----------------
// A given as hi/lo bf16 planes [M][K]; W as transposed hi/lo planes [N][K].
template <int BN>  // 128 or 64
__global__ __launch_bounds__(256) void gemm_mfma_k(
    const ushort_t* __restrict__ Ahi, const ushort_t* __restrict__ Alo,
    const ushort_t* __restrict__ Bhi, const ushort_t* __restrict__ Blo,
    float* __restrict__ C, int M, int K, int N, const float* __restrict__ ns) {
    constexpr int BM = 128, BK = 32;
    constexpr int WN = (BN == 128) ? 2 : 1;          // waves along N
    constexpr int TM = BM / ((4 / WN) * 16);         // tiles per wave along M (4 or 2)
    constexpr int TN = BN / (WN * 16);               // tiles per wave along N (4)
    __shared__ __attribute__((aligned(16))) ushort_t Ah[BM * BK];
    __shared__ __attribute__((aligned(16))) ushort_t Al[BM * BK];
    __shared__ __attribute__((aligned(16))) ushort_t Bh[BN * BK];
    __shared__ __attribute__((aligned(16))) ushort_t Bl[BN * BK];
    const int t = threadIdx.x;
    const int wave = t >> 6, lane = t & 63;
    const int quad = lane >> 4, l16 = lane & 15;
    const int m0 = blockIdx.x * BM, n0 = blockIdx.y * BN;
    const int wrow = (wave / WN) * (TM * 16);
    const int wcol = (wave % WN) * (TN * 16);

    f32x4 acc[TM][TN];
#pragma unroll
    for (int mi = 0; mi < TM; ++mi)
#pragma unroll
        for (int ni = 0; ni < TN; ++ni) acc[mi][ni] = (f32x4){0.f, 0.f, 0.f, 0.f};

    for (int k0 = 0; k0 < K; k0 += BK) {
        // ---- stage A: 512 chunks of 8 bf16; chunk c -> row c>>2, k-octet c&3
#pragma unroll
        for (int j = 0; j < 2; ++j) {
            int c = t + j * 256;
            int r = c >> 2, q = c & 3;
            int gr = m0 + r;
            if (gr >= M) gr = M - 1;
            size_t goff = (size_t)gr * K + k0 + q * 8;
            *(short8*)&Ah[c * 8] = *(const short8*)&Ahi[goff];
            *(short8*)&Al[c * 8] = *(const short8*)&Alo[goff];
        }
        // ---- stage B: BN*4 chunks
#pragma unroll
        for (int j = 0; j < BN / 64; ++j) {
            int c = t + j * 256;
            int r = c >> 2, q = c & 3;
            size_t goff = (size_t)(n0 + r) * K + k0 + q * 8;
            *(short8*)&Bh[c * 8] = *(const short8*)&Bhi[goff];
            *(short8*)&Bl[c * 8] = *(const short8*)&Blo[goff];
        }
        __syncthreads();
        // ---- fragments: A[m=l16][k=quad*8+j], B[k=quad*8+j][n=l16]
        short8 afh[TM], afl[TM], bfh[TN], bfl[TN];
#pragma unroll
        for (int mi = 0; mi < TM; ++mi) {
            int m = wrow + mi * 16 + l16;
            afh[mi] = *(const short8*)&Ah[m * BK + quad * 8];
            afl[mi] = *(const short8*)&Al[m * BK + quad * 8];
        }
#pragma unroll
        for (int ni = 0; ni < TN; ++ni) {
            int n = wcol + ni * 16 + l16;
            bfh[ni] = *(const short8*)&Bh[n * BK + quad * 8];
            bfl[ni] = *(const short8*)&Bl[n * BK + quad * 8];
        }
#pragma unroll
        for (int mi = 0; mi < TM; ++mi)
#pragma unroll
            for (int ni = 0; ni < TN; ++ni) {
                acc[mi][ni] = __builtin_amdgcn_mfma_f32_16x16x32_bf16(afh[mi], bfh[ni],
                                                                      acc[mi][ni], 0, 0, 0);
                acc[mi][ni] = __builtin_amdgcn_mfma_f32_16x16x32_bf16(afh[mi], bfl[ni],
                                                                      acc[mi][ni], 0, 0, 0);
                acc[mi][ni] = __builtin_amdgcn_mfma_f32_16x16x32_bf16(afl[mi], bfh[ni],
                                                                      acc[mi][ni], 0, 0, 0);
            }
        __syncthreads();
    }
    // ---- epilogue: C/D layout col=l16, row=quad*4+reg; scale by ns
#pragma unroll
    for (int mi = 0; mi < TM; ++mi)
#pragma unroll
        for (int r = 0; r < 4; ++r) {
            int row = m0 + wrow + mi * 16 + quad * 4 + r;
            if (row < M) {
                float s = ns[row];
#pragma unroll
                for (int ni = 0; ni < TN; ++ni) {
                    C[(size_t)row * N + n0 + wcol + ni * 16 + l16] = acc[mi][ni][r] * s;
                }
            }
        }
}

// ---------------- CSR aggregation + fused epilogue ----------------
// res = act(nd[w] * sum_{e: dst==w} tmp[src[e]] + bias)
// OUT_MODE: 0 = fp32 only, 1 = hi/lo planes only, 2 = both
template <int VEC, int RELU, int OUT_MODE>
__global__ void agg_ep_k(const float* __restrict__ tmp, float* __restrict__ outF,
                         ushort_t* __restrict__ outH, ushort_t* __restrict__ outL,
                         const int* __restrict__ row_start, const int* __restrict__ edge_src,
                         const float* __restrict__ nd, const float* __restrict__ bias,
                         int n_nodes, int dim) {
    int w = (blockIdx.x * blockDim.x + threadIdx.x) >> 6;
    int lane = threadIdx.x & 63;
    if (w >= n_nodes) return;
    int s = row_start[w], e = row_start[w + 1];
    int col = lane * VEC;
    float acc0[VEC], acc1[VEC];
#pragma unroll
    for (int j = 0; j < VEC; ++j) { acc0[j] = 0.f; acc1[j] = 0.f; }
    int i = s;
    for (; i + 1 < e; i += 2) {
        int u0 = edge_src[i];
        int u1 = edge_src[i + 1];
        const float* p0 = tmp + (size_t)u0 * dim + col;
        const float* p1 = tmp + (size_t)u1 * dim + col;
        if (VEC == 4) {
            float4 v0 = *(const float4*)p0;
            float4 v1 = *(const float4*)p1;
            acc0[0] += v0.x; acc0[1] += v0.y; acc0[2] += v0.z; acc0[3] += v0.w;
            acc1[0] += v1.x; acc1[1] += v1.y; acc1[2] += v1.z; acc1[3] += v1.w;
        } else if (VEC == 2) {
            float2 v0 = *(const float2*)p0;
            float2 v1 = *(const float2*)p1;
            acc0[0] += v0.x; acc0[1] += v0.y;
            acc1[0] += v1.x; acc1[1] += v1.y;
        } else {
            acc0[0] += *p0;
            acc1[0] += *p1;
        }
    }
    if (i < e) {
        int u = edge_src[i];
        const float* p = tmp + (size_t)u * dim + col;
        if (VEC == 4) {
            float4 v = *(const float4*)p;
            acc0[0] += v.x; acc0[1] += v.y; acc0[2] += v.z; acc0[3] += v.w;
        } else if (VEC == 2) {
            float2 v = *(const float2*)p;
            acc0[0] += v.x; acc0[1] += v.y;
        } else {
            acc0[0] += *p;
        }
    }
    float d = nd[w];
    float r[VEC];
#pragma unroll
    for (int j = 0; j < VEC; ++j) {
        float v = fmaf(acc0[j] + acc1[j], d, bias[col + j]);
        r[j] = RELU ? fmaxf(v, 0.f) : v;
    }
    size_t base = (size_t)w * dim + col;
    if (OUT_MODE != 1) {
        if (VEC == 4) {
            *(float4*)(outF + base) = make_float4(r[0], r[1], r[2], r[3]);
        } else if (VEC == 2) {
            *(float2*)(outF + base) = make_float2(r[0], r[1]);
        } else {
            outF[base] = r[0];
        }
    }
    if (OUT_MODE != 0) {
        ushort_t h[VEC], l[VEC];
#pragma unroll
        for (int j = 0; j < VEC; ++j) split1(r[j], h[j], l[j]);
        if (VEC == 4) {
            *(ushort4*)(outH + base) = make_ushort4(h[0], h[1], h[2], h[3]);
            *(ushort4*)(outL + base) = make_ushort4(l[0], l[1], l[2], l[3]);
        } else if (VEC == 2) {
            *(ushort2*)(outH + base) = make_ushort2(h[0], h[1]);
            *(ushort2*)(outL + base) = make_ushort2(l[0], l[1]);
        } else {
            outH[base] = h[0];
            outL[base] = l[0];
        }
    }
}

extern "C" void kernel_launch(void* const* d_in, const int* in_sizes, int n_in,
                              void* d_out, int out_size, void* d_ws, size_t ws_size,
                              hipStream_t stream) {
    const float* features = (const float*)d_in[0];
    const int* src = (const int*)d_in[1];
    const int* dst = (const int*)d_in[2];
    const float* W0 = (const float*)d_in[3];
    const float* b0 = (const float*)d_in[4];
    const float* W1 = (const float*)d_in[5];
    const float* b1 = (const float*)d_in[6];
    const float* W2 = (const float*)d_in[7];
    const float* b2 = (const float*)d_in[8];
    const float* W3 = (const float*)d_in[9];
    const float* b3 = (const float*)d_in[10];
    float* out = (float*)d_out;

    // workspace carve (~158 MB)
    char* p = (char*)d_ws;
    auto alloc = [&](size_t bytes) {
        void* r = (void*)p;
        p += (bytes + 255) & ~(size_t)255;
        return r;
    };
    float* tmp = (float*)alloc((size_t)N_NODES * 256 * 4);          // 51.2 MB GEMM out
    char* planes = (char*)alloc((size_t)N_NODES * 512 * 2 * 2);     // 102.4 MB hi/lo region
    ushort_t* Fhi = (ushort_t*)planes;                               // [M][512]
    ushort_t* Flo = Fhi + (size_t)N_NODES * 512;
    // H1/H3 planes at region offset 0 (F dead by then), H2 at +51.2 MB
    ushort_t* H1hi = (ushort_t*)planes;                              // [M][256]
    ushort_t* H1lo = H1hi + (size_t)N_NODES * 256;
    ushort_t* H2hi = (ushort_t*)(planes + (size_t)N_NODES * 512 * 2);  // [M][256]
    ushort_t* H2lo = H2hi + (size_t)N_NODES * 256;
    ushort_t* H3hi = (ushort_t*)planes;                              // [M][128]
    ushort_t* H3lo = H3hi + (size_t)N_NODES * 128;
    ushort_t* W0hi = (ushort_t*)alloc(512 * 256 * 2);  // Wt planes [N][K]
    ushort_t* W0lo = (ushort_t*)alloc(512 * 256 * 2);
    ushort_t* W1hi = (ushort_t*)alloc(256 * 256 * 2);
    ushort_t* W1lo = (ushort_t*)alloc(256 * 256 * 2);
    ushort_t* W2hi = (ushort_t*)alloc(256 * 128 * 2);
    ushort_t* W2lo = (ushort_t*)alloc(256 * 128 * 2);
    ushort_t* W3hi = (ushort_t*)alloc(128 * 64 * 2);
    ushort_t* W3lo = (ushort_t*)alloc(128 * 64 * 2);
    int* edge_src = (int*)alloc((size_t)N_EDGES * 4);
    int* row_start = (int*)alloc((size_t)(N_NODES + 1) * 4);
    int* cursor = (int*)alloc((size_t)N_NODES * 4);
    int* degO = (int*)alloc((size_t)N_NODES * 4);
    int* degI = (int*)alloc((size_t)N_NODES * 4);
    float* ns = (float*)alloc((size_t)N_NODES * 4);
    float* nd = (float*)alloc((size_t)N_NODES * 4);

    // ---- graph preprocessing ----
    hipMemsetAsync(degO, 0, (size_t)N_NODES * 4, stream);
    hipMemsetAsync(degI, 0, (size_t)N_NODES * 4, stream);
    count_deg_k<<<(N_EDGES + 255) / 256, 256, 0, stream>>>(src, dst, N_EDGES, degO, degI);
    norm_k<<<(N_NODES + 255) / 256, 256, 0, stream>>>(degO, degI, ns, nd, N_NODES);
    scan_k<<<1, 1024, 0, stream>>>(degI, row_start, cursor, N_NODES);
    fill_csr_k<<<(N_EDGES + 255) / 256, 256, 0, stream>>>(src, dst, N_EDGES, cursor, edge_src);

    // ---- input splits ----
    {
        int n4 = N_NODES * 512 / 4;
        split4_k<<<(n4 + 255) / 256, 256, 0, stream>>>(features, Fhi, Flo, n4);
    }
    split_wt_k<<<(512 * 256 + 255) / 256, 256, 0, stream>>>(W0, W0hi, W0lo, 512, 256);
    split_wt_k<<<(256 * 256 + 255) / 256, 256, 0, stream>>>(W1, W1hi, W1lo, 256, 256);
    split_wt_k<<<(256 * 128 + 255) / 256, 256, 0, stream>>>(W2, W2hi, W2lo, 256, 128);
    split_wt_k<<<(128 * 64 + 255) / 256, 256, 0, stream>>>(W3, W3hi, W3lo, 128, 64);

    const int gm = (N_NODES + 127) / 128;     // 391
    const int aggBlocks = (N_NODES + 3) / 4;  // 4 waves/block

    // ---- layer 0: 512 -> 256 ----
    gemm_mfma_k<128><<<dim3(gm, 2), 256, 0, stream>>>(Fhi, Flo, W0hi, W0lo, tmp,
                                                      N_NODES, 512, 256, ns);
    agg_ep_k<4, 1, 1><<<aggBlocks, 256, 0, stream>>>(tmp, nullptr, H1hi, H1lo, row_start,
                                                     edge_src, nd, b0, N_NODES, 256);

    // ---- layer 1: 256 -> 256 ----
    gemm_mfma_k<128><<<dim3(gm, 2), 256, 0, stream>>>(H1hi, H1lo, W1hi, W1lo, tmp,
                                                      N_NODES, 256, 256, ns);
    agg_ep_k<4, 1, 1><<<aggBlocks, 256, 0, stream>>>(tmp, nullptr, H2hi, H2lo, row_start,
                                                     edge_src, nd, b1, N_NODES, 256);

    // ---- layer 2: 256 -> 128 (aspect_embed -> d_out, planes for L3) ----
    gemm_mfma_k<128><<<dim3(gm, 1), 256, 0, stream>>>(H2hi, H2lo, W2hi, W2lo, tmp,
                                                      N_NODES, 256, 128, ns);
    agg_ep_k<2, 0, 2><<<aggBlocks, 256, 0, stream>>>(tmp, out, H3hi, H3lo, row_start,
                                                     edge_src, nd, b2, N_NODES, 128);

    // ---- layer 3: 128 -> 64 (h -> d_out + 50000*128) ----
    gemm_mfma_k<64><<<dim3(gm, 1), 256, 0, stream>>>(H3hi, H3lo, W3hi, W3lo, tmp,
                                                     N_NODES, 128, 64, ns);
    agg_ep_k<1, 0, 0><<<aggBlocks, 256, 0, stream>>>(tmp, out + (size_t)N_NODES * 128,
                                                     nullptr, nullptr, row_start, edge_src,
                                                     nd, b3, N_NODES, 64);
}

// Round 4
// 635.243 us; speedup vs baseline: 1.7898x; 1.3618x over previous
//
#include <hip/hip_runtime.h>
#include <hip/hip_bf16.h>
#include <hip/hip_fp16.h>

#define N_NODES 50000
#define N_EDGES 800000

typedef unsigned short ushort_t;
typedef unsigned int uint_t;
typedef __attribute__((ext_vector_type(8))) short short8;
typedef __attribute__((ext_vector_type(4))) float f32x4;

// ---------------- bf16 split helpers ----------------
__device__ inline ushort_t bf16_rne(float x) {
    uint_t u = __float_as_uint(x);
    uint_t r = (u + 0x7fffu + ((u >> 16) & 1u)) >> 16;
    return (ushort_t)r;
}
__device__ inline void split1(float x, ushort_t& h, ushort_t& l) {
    ushort_t hh = bf16_rne(x);
    float fh = __uint_as_float((uint_t)hh << 16);
    h = hh;
    l = bf16_rne(x - fh);
}

// ---------------- degree count ----------------
__global__ void count_deg_k(const int* __restrict__ src, const int* __restrict__ dst,
                            int n_edges, int* __restrict__ deg_out, int* __restrict__ deg_in) {
    int i = blockIdx.x * blockDim.x + threadIdx.x;
    if (i < n_edges) {
        atomicAdd(&deg_out[src[i]], 1);
        atomicAdd(&deg_in[dst[i]], 1);
    }
}

// ---------------- norms ----------------
__global__ void norm_k(const int* __restrict__ deg_out, const int* __restrict__ deg_in,
                       float* __restrict__ ns, float* __restrict__ nd, int n) {
    int i = blockIdx.x * blockDim.x + threadIdx.x;
    if (i < n) {
        ns[i] = 1.0f / sqrtf((float)max(deg_out[i], 1));
        nd[i] = 1.0f / sqrtf((float)max(deg_in[i], 1));
    }
}

// ---------------- exclusive scan (single block, shfl-based) ----------------
__global__ void scan_k(const int* __restrict__ deg, int* __restrict__ row_start,
                       int* __restrict__ cursor, int n) {
    __shared__ int wexcl[16];
    __shared__ int chunk_total;
    __shared__ int carry_s;
    const int tid = threadIdx.x;
    const int lane = tid & 63, wid = tid >> 6;
    if (tid == 0) carry_s = 0;
    for (int base = 0; base < n; base += 1024) {
        int i = base + tid;
        int v = (i < n) ? deg[i] : 0;
        // inclusive wave scan
        int x = v;
#pragma unroll
        for (int off = 1; off < 64; off <<= 1) {
            int y = __shfl_up(x, off, 64);
            if (lane >= off) x += y;
        }
        __syncthreads();  // protect wexcl reuse across chunks; orders carry_s update
        if (lane == 63) wexcl[wid] = x;
        __syncthreads();
        if (wid == 0) {
            int tv = (lane < 16) ? wexcl[lane] : 0;
            int xs = tv;
#pragma unroll
            for (int off = 1; off < 16; off <<= 1) {
                int y = __shfl_up(xs, off, 64);
                if (lane >= off) xs += y;
            }
            if (lane < 16) wexcl[lane] = xs - tv;  // exclusive wave offset
            if (lane == 15) chunk_total = xs;
        }
        __syncthreads();
        int carry = carry_s;
        if (i < n) {
            int o = carry + wexcl[wid] + x - v;
            row_start[i] = o;
            cursor[i] = o;
        }
        __syncthreads();  // all reads of carry_s done
        if (tid == 0) carry_s = carry + chunk_total;
    }
    if (tid == 0) row_start[n] = carry_s;
}

// ---------------- CSR fill ----------------
__global__ void fill_csr_k(const int* __restrict__ src, const int* __restrict__ dst,
                           int n_edges, int* __restrict__ cursor, int* __restrict__ edge_src) {
    int i = blockIdx.x * blockDim.x + threadIdx.x;
    if (i < n_edges) {
        int pos = atomicAdd(&cursor[dst[i]], 1);
        edge_src[pos] = src[i];
    }
}

// ---------------- split+transpose all 4 weights in one launch ----------------
__global__ void split_weights_k(const float* __restrict__ W0, const float* __restrict__ W1,
                                const float* __restrict__ W2, const float* __restrict__ W3,
                                ushort_t* __restrict__ W0h, ushort_t* __restrict__ W0l,
                                ushort_t* __restrict__ W1h, ushort_t* __restrict__ W1l,
                                ushort_t* __restrict__ W2h, ushort_t* __restrict__ W2l,
                                ushort_t* __restrict__ W3h, ushort_t* __restrict__ W3l) {
    const int s0 = 512 * 256, s1 = s0 + 256 * 256, s2 = s1 + 256 * 128, s3 = s2 + 128 * 64;
    int idx = blockIdx.x * blockDim.x + threadIdx.x;
    const float* W;
    ushort_t *H, *L;
    int K, N, local;
    if (idx < s0) { W = W0; H = W0h; L = W0l; K = 512; N = 256; local = idx; }
    else if (idx < s1) { W = W1; H = W1h; L = W1l; K = 256; N = 256; local = idx - s0; }
    else if (idx < s2) { W = W2; H = W2h; L = W2l; K = 256; N = 128; local = idx - s1; }
    else if (idx < s3) { W = W3; H = W3h; L = W3l; K = 128; N = 64; local = idx - s2; }
    else return;
    int n = local / K;
    int k = local - n * K;
    split1(W[(size_t)k * N + n], H[local], L[local]);
}

// ---------------- MFMA GEMM: C[M,N] = fp16( ns[row] * (A @ W) ), bf16x2 3-pass ----
// ASRC=0: A as hi/lo bf16 planes [M][K]. ASRC=1: A fp32 [M][K], split inline.
// W as transposed hi/lo planes [N][K].
template <int BN, int ASRC>  // BN: 128 or 64
__global__ __launch_bounds__(256) void gemm_mfma_k(
    const float* __restrict__ Af,
    const ushort_t* __restrict__ Ahi, const ushort_t* __restrict__ Alo,
    const ushort_t* __restrict__ Bhi, const ushort_t* __restrict__ Blo,
    __half* __restrict__ C, int M, int K, int N, const float* __restrict__ ns) {
    constexpr int BM = 128, BK = 32;
    constexpr int WN = (BN == 128) ? 2 : 1;
    constexpr int TM = BM / ((4 / WN) * 16);
    constexpr int TN = BN / (WN * 16);
    __shared__ __attribute__((aligned(16))) ushort_t Ah[BM * BK];
    __shared__ __attribute__((aligned(16))) ushort_t Al[BM * BK];
    __shared__ __attribute__((aligned(16))) ushort_t Bh[BN * BK];
    __shared__ __attribute__((aligned(16))) ushort_t Bl[BN * BK];
    const int t = threadIdx.x;
    const int wave = t >> 6, lane = t & 63;
    const int quad = lane >> 4, l16 = lane & 15;
    const int m0 = blockIdx.x * BM, n0 = blockIdx.y * BN;
    const int wrow = (wave / WN) * (TM * 16);
    const int wcol = (wave % WN) * (TN * 16);

    f32x4 acc[TM][TN];
#pragma unroll
    for (int mi = 0; mi < TM; ++mi)
#pragma unroll
        for (int ni = 0; ni < TN; ++ni) acc[mi][ni] = (f32x4){0.f, 0.f, 0.f, 0.f};

    for (int k0 = 0; k0 < K; k0 += BK) {
        // ---- stage A: 512 chunks of 8 bf16; chunk c -> row c>>2, k-octet c&3
        if (ASRC == 0) {
#pragma unroll
            for (int j = 0; j < 2; ++j) {
                int c = t + j * 256;
                int r = c >> 2, q = c & 3;
                int gr = m0 + r;
                if (gr >= M) gr = M - 1;
                size_t goff = (size_t)gr * K + k0 + q * 8;
                *(short8*)&Ah[c * 8] = *(const short8*)&Ahi[goff];
                *(short8*)&Al[c * 8] = *(const short8*)&Alo[goff];
            }
        } else {
#pragma unroll
            for (int j = 0; j < 2; ++j) {
                int c = t + j * 256;
                int r = c >> 2, q = c & 3;
                int gr = m0 + r;
                if (gr >= M) gr = M - 1;
                const float* ap = Af + (size_t)gr * K + k0 + q * 8;
                float4 v0 = *(const float4*)ap;
                float4 v1 = *(const float4*)(ap + 4);
                float vv[8] = {v0.x, v0.y, v0.z, v0.w, v1.x, v1.y, v1.z, v1.w};
                short8 hh, ll;
#pragma unroll
                for (int ee = 0; ee < 8; ++ee) {
                    ushort_t h, l;
                    split1(vv[ee], h, l);
                    hh[ee] = (short)h;
                    ll[ee] = (short)l;
                }
                *(short8*)&Ah[c * 8] = hh;
                *(short8*)&Al[c * 8] = ll;
            }
        }
        // ---- stage B: BN*4 chunks
#pragma unroll
        for (int j = 0; j < BN / 64; ++j) {
            int c = t + j * 256;
            int r = c >> 2, q = c & 3;
            size_t goff = (size_t)(n0 + r) * K + k0 + q * 8;
            *(short8*)&Bh[c * 8] = *(const short8*)&Bhi[goff];
            *(short8*)&Bl[c * 8] = *(const short8*)&Blo[goff];
        }
        __syncthreads();
        // ---- fragments: A[m=l16][k=quad*8+j], B[k=quad*8+j][n=l16]
        short8 afh[TM], afl[TM], bfh[TN], bfl[TN];
#pragma unroll
        for (int mi = 0; mi < TM; ++mi) {
            int m = wrow + mi * 16 + l16;
            afh[mi] = *(const short8*)&Ah[m * BK + quad * 8];
            afl[mi] = *(const short8*)&Al[m * BK + quad * 8];
        }
#pragma unroll
        for (int ni = 0; ni < TN; ++ni) {
            int n = wcol + ni * 16 + l16;
            bfh[ni] = *(const short8*)&Bh[n * BK + quad * 8];
            bfl[ni] = *(const short8*)&Bl[n * BK + quad * 8];
        }
#pragma unroll
        for (int mi = 0; mi < TM; ++mi)
#pragma unroll
            for (int ni = 0; ni < TN; ++ni) {
                acc[mi][ni] = __builtin_amdgcn_mfma_f32_16x16x32_bf16(afh[mi], bfh[ni],
                                                                      acc[mi][ni], 0, 0, 0);
                acc[mi][ni] = __builtin_amdgcn_mfma_f32_16x16x32_bf16(afh[mi], bfl[ni],
                                                                      acc[mi][ni], 0, 0, 0);
                acc[mi][ni] = __builtin_amdgcn_mfma_f32_16x16x32_bf16(afl[mi], bfh[ni],
                                                                      acc[mi][ni], 0, 0, 0);
            }
        __syncthreads();
    }
    // ---- epilogue: C/D layout col=l16, row=quad*4+reg; scale by ns, emit fp16
#pragma unroll
    for (int mi = 0; mi < TM; ++mi)
#pragma unroll
        for (int r = 0; r < 4; ++r) {
            int row = m0 + wrow + mi * 16 + quad * 4 + r;
            if (row < M) {
                float s = ns[row];
#pragma unroll
                for (int ni = 0; ni < TN; ++ni) {
                    C[(size_t)row * N + n0 + wcol + ni * 16 + l16] =
                        __float2half(acc[mi][ni][r] * s);
                }
            }
        }
}

// ---------------- gather-row add helper ----------------
template <int VEC>
__device__ inline void load_add(float* a, const __half* p) {
    if (VEC == 4) {
        uint2 r = *(const uint2*)p;
        __half2 h0 = *reinterpret_cast<__half2*>(&r.x);
        __half2 h1 = *reinterpret_cast<__half2*>(&r.y);
        float2 f0 = __half22float2(h0);
        float2 f1 = __half22float2(h1);
        a[0] += f0.x; a[1] += f0.y; a[2] += f1.x; a[3] += f1.y;
    } else if (VEC == 2) {
        uint_t r = *(const uint_t*)p;
        __half2 h0 = *reinterpret_cast<__half2*>(&r);
        float2 f0 = __half22float2(h0);
        a[0] += f0.x; a[1] += f0.y;
    } else {
        a[0] += __half2float(*p);
    }
}

// ---------------- CSR aggregation + fused epilogue ----------------
// res = act(nd[w] * sum_{e: dst==w} tmp[src[e]] + bias)
// OUT_MODE: 0 = fp32 only, 1 = hi/lo planes only, 2 = both
template <int VEC, int RELU, int OUT_MODE>
__global__ void agg_ep_k(const __half* __restrict__ tmp, float* __restrict__ outF,
                         ushort_t* __restrict__ outH, ushort_t* __restrict__ outL,
                         const int* __restrict__ row_start, const int* __restrict__ edge_src,
                         const float* __restrict__ nd, const float* __restrict__ bias,
                         int n_nodes, int dim) {
    int w = (blockIdx.x * blockDim.x + threadIdx.x) >> 6;
    int lane = threadIdx.x & 63;
    if (w >= n_nodes) return;
    int s = row_start[w], e = row_start[w + 1];
    int col = lane * VEC;
    float acc[4][VEC];
#pragma unroll
    for (int c = 0; c < 4; ++c)
#pragma unroll
        for (int j = 0; j < VEC; ++j) acc[c][j] = 0.f;
    int i = s;
    for (; i + 3 < e; i += 4) {
        int u0 = edge_src[i];
        int u1 = edge_src[i + 1];
        int u2 = edge_src[i + 2];
        int u3 = edge_src[i + 3];
        load_add<VEC>(acc[0], tmp + (size_t)u0 * dim + col);
        load_add<VEC>(acc[1], tmp + (size_t)u1 * dim + col);
        load_add<VEC>(acc[2], tmp + (size_t)u2 * dim + col);
        load_add<VEC>(acc[3], tmp + (size_t)u3 * dim + col);
    }
    for (; i < e; ++i) {
        int u = edge_src[i];
        load_add<VEC>(acc[0], tmp + (size_t)u * dim + col);
    }
    float d = nd[w];
    float r[VEC];
#pragma unroll
    for (int j = 0; j < VEC; ++j) {
        float v = fmaf((acc[0][j] + acc[1][j]) + (acc[2][j] + acc[3][j]), d, bias[col + j]);
        r[j] = RELU ? fmaxf(v, 0.f) : v;
    }
    size_t base = (size_t)w * dim + col;
    if (OUT_MODE != 1) {
        if (VEC == 4) {
            *(float4*)(outF + base) = make_float4(r[0], r[1], r[2], r[3]);
        } else if (VEC == 2) {
            *(float2*)(outF + base) = make_float2(r[0], r[1]);
        } else {
            outF[base] = r[0];
        }
    }
    if (OUT_MODE != 0) {
        ushort_t h[VEC], l[VEC];
#pragma unroll
        for (int j = 0; j < VEC; ++j) split1(r[j], h[j], l[j]);
        if (VEC == 4) {
            *(ushort4*)(outH + base) = make_ushort4(h[0], h[1], h[2], h[3]);
            *(ushort4*)(outL + base) = make_ushort4(l[0], l[1], l[2], l[3]);
        } else if (VEC == 2) {
            *(ushort2*)(outH + base) = make_ushort2(h[0], h[1]);
            *(ushort2*)(outL + base) = make_ushort2(l[0], l[1]);
        } else {
            outH[base] = h[0];
            outL[base] = l[0];
        }
    }
}

extern "C" void kernel_launch(void* const* d_in, const int* in_sizes, int n_in,
                              void* d_out, int out_size, void* d_ws, size_t ws_size,
                              hipStream_t stream) {
    const float* features = (const float*)d_in[0];
    const int* src = (const int*)d_in[1];
    const int* dst = (const int*)d_in[2];
    const float* W0 = (const float*)d_in[3];
    const float* b0 = (const float*)d_in[4];
    const float* W1 = (const float*)d_in[5];
    const float* b1 = (const float*)d_in[6];
    const float* W2 = (const float*)d_in[7];
    const float* b2 = (const float*)d_in[8];
    const float* W3 = (const float*)d_in[9];
    const float* b3 = (const float*)d_in[10];
    float* out = (float*)d_out;

    // workspace carve (~160 MB)
    char* p = (char*)d_ws;
    auto alloc = [&](size_t bytes) {
        void* r = (void*)p;
        p += (bytes + 255) & ~(size_t)255;
        return r;
    };
    __half* tmp = (__half*)alloc((size_t)N_NODES * 256 * 2);        // 25.6 MB GEMM out (fp16)
    ushort_t* H1hi = (ushort_t*)alloc((size_t)N_NODES * 256 * 2);   // [M][256]
    ushort_t* H1lo = (ushort_t*)alloc((size_t)N_NODES * 256 * 2);
    ushort_t* H2hi = (ushort_t*)alloc((size_t)N_NODES * 256 * 2);   // [M][256]
    ushort_t* H2lo = (ushort_t*)alloc((size_t)N_NODES * 256 * 2);
    ushort_t* H3hi = (ushort_t*)alloc((size_t)N_NODES * 128 * 2);   // [M][128]
    ushort_t* H3lo = (ushort_t*)alloc((size_t)N_NODES * 128 * 2);
    ushort_t* W0hi = (ushort_t*)alloc(512 * 256 * 2);               // Wt planes [N][K]
    ushort_t* W0lo = (ushort_t*)alloc(512 * 256 * 2);
    ushort_t* W1hi = (ushort_t*)alloc(256 * 256 * 2);
    ushort_t* W1lo = (ushort_t*)alloc(256 * 256 * 2);
    ushort_t* W2hi = (ushort_t*)alloc(256 * 128 * 2);
    ushort_t* W2lo = (ushort_t*)alloc(256 * 128 * 2);
    ushort_t* W3hi = (ushort_t*)alloc(128 * 64 * 2);
    ushort_t* W3lo = (ushort_t*)alloc(128 * 64 * 2);
    int* edge_src = (int*)alloc((size_t)N_EDGES * 4);
    int* row_start = (int*)alloc((size_t)(N_NODES + 1) * 4);
    int* cursor = (int*)alloc((size_t)N_NODES * 4);
    int* degO = (int*)alloc((size_t)N_NODES * 4);
    int* degI = (int*)alloc((size_t)N_NODES * 4);
    float* ns = (float*)alloc((size_t)N_NODES * 4);
    float* nd = (float*)alloc((size_t)N_NODES * 4);

    // ---- graph preprocessing ----
    hipMemsetAsync(degO, 0, (size_t)N_NODES * 4, stream);
    hipMemsetAsync(degI, 0, (size_t)N_NODES * 4, stream);
    count_deg_k<<<(N_EDGES + 255) / 256, 256, 0, stream>>>(src, dst, N_EDGES, degO, degI);
    norm_k<<<(N_NODES + 255) / 256, 256, 0, stream>>>(degO, degI, ns, nd, N_NODES);
    scan_k<<<1, 1024, 0, stream>>>(degI, row_start, cursor, N_NODES);
    fill_csr_k<<<(N_EDGES + 255) / 256, 256, 0, stream>>>(src, dst, N_EDGES, cursor, edge_src);

    // ---- weight splits (one launch) ----
    {
        const int tot = 512 * 256 + 256 * 256 + 256 * 128 + 128 * 64;
        split_weights_k<<<(tot + 255) / 256, 256, 0, stream>>>(
            W0, W1, W2, W3, W0hi, W0lo, W1hi, W1lo, W2hi, W2lo, W3hi, W3lo);
    }

    const int gm = (N_NODES + 127) / 128;     // 391
    const int aggBlocks = (N_NODES + 3) / 4;  // 4 waves/block

    // ---- layer 0: 512 -> 256 (feature split fused into staging) ----
    gemm_mfma_k<128, 1><<<dim3(gm, 2), 256, 0, stream>>>(features, nullptr, nullptr,
                                                         W0hi, W0lo, tmp, N_NODES, 512, 256, ns);
    agg_ep_k<4, 1, 1><<<aggBlocks, 256, 0, stream>>>(tmp, nullptr, H1hi, H1lo, row_start,
                                                     edge_src, nd, b0, N_NODES, 256);

    // ---- layer 1: 256 -> 256 ----
    gemm_mfma_k<128, 0><<<dim3(gm, 2), 256, 0, stream>>>(nullptr, H1hi, H1lo, W1hi, W1lo,
                                                         tmp, N_NODES, 256, 256, ns);
    agg_ep_k<4, 1, 1><<<aggBlocks, 256, 0, stream>>>(tmp, nullptr, H2hi, H2lo, row_start,
                                                     edge_src, nd, b1, N_NODES, 256);

    // ---- layer 2: 256 -> 128 (aspect_embed -> d_out, planes for L3) ----
    gemm_mfma_k<128, 0><<<dim3(gm, 1), 256, 0, stream>>>(nullptr, H2hi, H2lo, W2hi, W2lo,
                                                         tmp, N_NODES, 256, 128, ns);
    agg_ep_k<2, 0, 2><<<aggBlocks, 256, 0, stream>>>(tmp, out, H3hi, H3lo, row_start,
                                                     edge_src, nd, b2, N_NODES, 128);

    // ---- layer 3: 128 -> 64 (h -> d_out + 50000*128) ----
    gemm_mfma_k<64, 0><<<dim3(gm, 1), 256, 0, stream>>>(nullptr, H3hi, H3lo, W3hi, W3lo,
                                                        tmp, N_NODES, 128, 64, ns);
    agg_ep_k<1, 0, 0><<<aggBlocks, 256, 0, stream>>>(tmp, out + (size_t)N_NODES * 128,
                                                     nullptr, nullptr, row_start, edge_src,
                                                     nd, b3, N_NODES, 64);
}